// Round 6
// baseline (540.197 us; speedup 1.0000x reference)
//
#include <hip/hip_runtime.h>
#include <hip/hip_bf16.h>
#include <stdint.h>
#include <stddef.h>

#define NSP 110592      // 48^3
#define SD  48
#define SD2 2304        // 48*48
#define CIN 128
#define C3  384
#define NH  8
#define NB  2
#define NQ  84934656ull // NB*C3*NSP

typedef __hip_bfloat16 bf16;
typedef __bf16 bf16x8 __attribute__((ext_vector_type(8)));
typedef float  f32x4  __attribute__((ext_vector_type(4)));

// wbuf element offsets (all bf16): qkvw | dww | projw | temp
#define WOFF_QKVW 0
#define WOFF_DWW  49152
#define WOFF_PROJ 59520
#define WOFF_TEMP 75904
#define WTOTAL    75912

__device__ __forceinline__ float ldb(const bf16* p){ return __bfloat162float(*p); }
__device__ __forceinline__ float b2f(uint16_t u){
    union { float f; uint32_t i; } x; x.i = (uint32_t)u << 16; return x.f;
}
__device__ __forceinline__ uint16_t f2b(float f){
    bf16 h = __float2bfloat16(f); return *(uint16_t*)&h;
}

// ---- sniffer: flag=1 if inputs are fp32, 0 if bf16 ---------------------------
__global__ void k_sniff(const uint16_t* __restrict__ x16, int* __restrict__ flag)
{
    int t = threadIdx.x; int cnt = 0;
    for (int i = 0; i < 16; ++i) {
        uint16_t b = x16[(size_t)(t * 16 + i) * 2];   // even halves only
        int e = (b >> 7) & 0xFF;
        if (e >= 100 && e <= 140) ++cnt;              // bf16-exponent-plausible
    }
    for (int off = 32; off; off >>= 1) cnt += __shfl_down(cnt, off, 64);
    __shared__ int s[4];
    if ((t & 63) == 0) s[t >> 6] = cnt;
    __syncthreads();
    if (t == 0) *flag = (s[0] + s[1] + s[2] + s[3] < 2048) ? 1 : 0;
}

// ---- canonicalize all weights to bf16 in wbuf --------------------------------
__global__ void k_cvtw(const void* __restrict__ qw, const void* __restrict__ dw,
                       const void* __restrict__ pw, const void* __restrict__ tw,
                       bf16* __restrict__ wbuf, const int* __restrict__ flagp)
{
    int f = *flagp;
    int idx = blockIdx.x * 256 + threadIdx.x;
    if (idx >= WTOTAL) return;
    const void* src; int off;
    if (idx < WOFF_DWW)      { src = qw; off = idx; }
    else if (idx < WOFF_PROJ){ src = dw; off = idx - WOFF_DWW; }
    else if (idx < WOFF_TEMP){ src = pw; off = idx - WOFF_PROJ; }
    else                     { src = tw; off = idx - WOFF_TEMP; }
    float v = f ? ((const float*)src)[off]
                : __bfloat162float(((const bf16*)src)[off]);
    wbuf[idx] = __float2bfloat16(v);
}

// ---- K1a: qkv GEMM with fused x-transpose staging ----------------------------
// C[b][m][n] = A[m][k] * x[b][k][n], K=128, 128x128 tiles, bf16 out.
// B-tile staged directly from x (fp32 or bf16 per flag): coalesced reads along
// n, 4x4 register transpose, ds_write_b64 into lB[n][c]. MFMA loop, LDS layout
// and C-write identical to the verified k_gemm_bt lineage.
__global__ __launch_bounds__(256) void k_gemm_qkv(const bf16* __restrict__ A,
                                                  const void* __restrict__ X,
                                                  bf16* __restrict__ Cout,
                                                  const int* __restrict__ flagp)
{
    __shared__ __align__(16) bf16 lA[128 * CIN];
    __shared__ __align__(16) bf16 lB[128 * CIN];
    int f = *flagp;
    int b = blockIdx.z;
    int bx = blockIdx.x;
    int g = bx / 24, w = bx % 24;
    int nb = g * 8 + (w & 7);          // mb-peers 8 blocks apart -> same XCD,
    int mb = w >> 3;                   // share the x tile in L2
    size_t nbase = (size_t)nb * 128;
    const bf16* gA = A + (size_t)mb * 128 * CIN;
    int t = threadIdx.x;

    // stage A (linear): 2048 uint4 = 8 per thread
#pragma unroll
    for (int i = 0; i < 8; ++i) {
        int idx = i * 256 + t;
        int r = idx >> 4, cc = idx & 15;
        *(uint4*)&lA[r * CIN + cc * 8] = *(const uint4*)&gA[r * CIN + cc * 8];
    }

    // stage B transposed from x[b][c][n]
    int cq = t >> 5;                   // 0..7
    int nq = t & 31;                   // 0..31
    if (f) {
        const float* xb = (const float*)X + (size_t)b * CIN * NSP + nbase;
#pragma unroll
        for (int p = 0; p < 4; ++p) {
            int c0 = p * 32 + cq * 4;
            float4 rv[4];
#pragma unroll
            for (int r = 0; r < 4; ++r)
                rv[r] = *(const float4*)&xb[(size_t)(c0 + r) * NSP + nq * 4];
#pragma unroll
            for (int e = 0; e < 4; ++e) {
                ushort4 o;
                o.x = f2b(((const float*)&rv[0])[e]);
                o.y = f2b(((const float*)&rv[1])[e]);
                o.z = f2b(((const float*)&rv[2])[e]);
                o.w = f2b(((const float*)&rv[3])[e]);
                *(ushort4*)&lB[(nq * 4 + e) * CIN + c0] = o;
            }
        }
    } else {
        const bf16* xb = (const bf16*)X + (size_t)b * CIN * NSP + nbase;
#pragma unroll
        for (int p = 0; p < 4; ++p) {
            int c0 = p * 32 + cq * 4;
            uint2 rv[4];
#pragma unroll
            for (int r = 0; r < 4; ++r)
                rv[r] = *(const uint2*)&xb[(size_t)(c0 + r) * NSP + nq * 4];
#pragma unroll
            for (int e = 0; e < 4; ++e) {
                ushort4 o;
                o.x = (uint16_t)(e < 2 ? (rv[0].x >> (e * 16)) : (rv[0].y >> ((e - 2) * 16)));
                o.y = (uint16_t)(e < 2 ? (rv[1].x >> (e * 16)) : (rv[1].y >> ((e - 2) * 16)));
                o.z = (uint16_t)(e < 2 ? (rv[2].x >> (e * 16)) : (rv[2].y >> ((e - 2) * 16)));
                o.w = (uint16_t)(e < 2 ? (rv[3].x >> (e * 16)) : (rv[3].y >> ((e - 2) * 16)));
                *(ushort4*)&lB[(nq * 4 + e) * CIN + c0] = o;
            }
        }
    }
    __syncthreads();

    int wave = t >> 6, lane = t & 63;
    int wm = (wave & 1) * 64, wn = (wave >> 1) * 64;
    int lr = lane & 15, lq = lane >> 4;
    f32x4 acc[4][4];
#pragma unroll
    for (int mi = 0; mi < 4; ++mi)
#pragma unroll
        for (int ni = 0; ni < 4; ++ni) acc[mi][ni] = (f32x4){0.f, 0.f, 0.f, 0.f};

#pragma unroll
    for (int ks = 0; ks < 4; ++ks) {
        int kof = ks * 32 + lq * 8;
        bf16x8 af[4], bfv[4];
#pragma unroll
        for (int mi = 0; mi < 4; ++mi)
            af[mi] = *(const bf16x8*)&lA[(wm + mi * 16 + lr) * CIN + kof];
#pragma unroll
        for (int ni = 0; ni < 4; ++ni)
            bfv[ni] = *(const bf16x8*)&lB[(wn + ni * 16 + lr) * CIN + kof];
#pragma unroll
        for (int mi = 0; mi < 4; ++mi)
#pragma unroll
            for (int ni = 0; ni < 4; ++ni)
                acc[mi][ni] = __builtin_amdgcn_mfma_f32_16x16x32_bf16(
                    af[mi], bfv[ni], acc[mi][ni], 0, 0, 0);
    }

    size_t cb = ((size_t)b * C3 + (size_t)mb * 128) * NSP + nbase;
    bf16* Cb = Cout + cb;
#pragma unroll
    for (int mi = 0; mi < 4; ++mi)
#pragma unroll
        for (int ni = 0; ni < 4; ++ni)
#pragma unroll
            for (int r = 0; r < 4; ++r)
                Cb[(size_t)(wm + mi * 16 + lq * 4 + r) * NSP + wn + ni * 16 + lr]
                    = __float2bfloat16(acc[mi][ni][r]);
}

// ---- K2: depthwise 3x3x3 conv, LDS-tiled, 4-wide vectorized strips -----------
// EXACT round-0 version (verified 154-160us, VGPR 80). Landmines found since:
//  * do NOT add a min-waves arg to __launch_bounds__ ((256,4) -> VGPR 64 ->
//    scratch spill in the hot loop -> 15x HBM amplification, 924us)
//  * do NOT use global_load_lds here (lane-dependent LDS dest)
//  * 96B-row/no-halo variant: fewer conflicts but more VGPR + stalls (224us)
#define PLN 3200        // 64*50
__global__ __launch_bounds__(256) void k_dwconv(const bf16* __restrict__ qkv1,
                                                const bf16* __restrict__ dw,
                                                bf16* __restrict__ qkv2,
                                                float* __restrict__ sums)
{
    __shared__ __align__(16) bf16 lds[8 * PLN];
    __shared__ float red[4];
    int bc = blockIdx.x;
    int slab = blockIdx.y;
    int z0 = slab * 6;
    int ch = bc % C3;
    int t = threadIdx.x;
    const bf16* src = qkv1 + (size_t)bc * NSP;
    bf16* dst = qkv2 + (size_t)bc * NSP;

    float wgt[27];
#pragma unroll
    for (int i = 0; i < 27; ++i) wgt[i] = ldb(&dw[ch * 27 + i]);

    // phase 0: zero all of LDS
#pragma unroll
    for (int i = 0; i < 13; ++i) {
        int idx = i * 256 + t;
        if (idx < 3200) *(uint4*)&lds[idx * 8] = (uint4){0, 0, 0, 0};
    }
    __syncthreads();

    // phase 1: stage 8 planes (z0-1 .. z0+6); 288 uint4 per plane
#pragma unroll
    for (int i = 0; i < 9; ++i) {
        int vidx = i * 256 + t;            // 0..2303
        int p = vidx / 288;
        int r = vidx - p * 288;
        int y = r / 6;
        int dg = r - y * 6;
        int zp = z0 - 1 + p;
        if ((unsigned)zp < SD) {
            uint4 v = *(const uint4*)&src[(size_t)zp * SD2 + y * SD + dg * 8];
            *(uint4*)&lds[(p * PLN + (y + 1) * 64 + 8 + dg * 8)] = v;
        }
    }
    __syncthreads();

    // phase 2: strips. 576 strips: strip s -> y = s/12, d-base = (s%12)*4.
    float ssq = 0.f;
#pragma unroll 1
    for (int r = 0; r < 3; ++r) {
        int s = r * 256 + t;
        if (s < 576) {                      // wave-uniform (residual = wave 0)
            int y = s / 12;
            int c4 = (s - y * 12) * 4;
            float acc[6][4];
#pragma unroll
            for (int oz = 0; oz < 6; ++oz)
#pragma unroll
                for (int d = 0; d < 4; ++d) acc[oz][d] = 0.f;

#pragma unroll
            for (int pl = 0; pl < 8; ++pl) {
                const uint16_t* P =
                    (const uint16_t*)lds + pl * PLN + y * 64 + 8 + c4;
                float v[3][6];
#pragma unroll
                for (int dy = 0; dy < 3; ++dy) {
                    const uint16_t* R = P + dy * 64;
                    uint2 m = *(const uint2*)R;            // d..d+3 (8B aligned)
                    v[dy][0] = b2f(R[-1]);
                    v[dy][1] = b2f((uint16_t)m.x);
                    v[dy][2] = b2f((uint16_t)(m.x >> 16));
                    v[dy][3] = b2f((uint16_t)m.y);
                    v[dy][4] = b2f((uint16_t)(m.y >> 16));
                    v[dy][5] = b2f(R[4]);
                }
                float p0[4] = {0.f,0.f,0.f,0.f};
                float p1[4] = {0.f,0.f,0.f,0.f};
                float p2[4] = {0.f,0.f,0.f,0.f};
#pragma unroll
                for (int dy = 0; dy < 3; ++dy)
#pragma unroll
                    for (int dd = 0; dd < 3; ++dd) {
                        float w0 = wgt[dy * 3 + dd];
                        float w1 = wgt[9 + dy * 3 + dd];
                        float w2 = wgt[18 + dy * 3 + dd];
#pragma unroll
                        for (int d = 0; d < 4; ++d) {
                            float xv = v[dy][d + dd];
                            if (pl <= 5)            p0[d] += w0 * xv;
                            if (pl >= 1 && pl <= 6) p1[d] += w1 * xv;
                            if (pl >= 2)            p2[d] += w2 * xv;
                        }
                    }
#pragma unroll
                for (int d = 0; d < 4; ++d) {
                    if (pl <= 5)            acc[pl][d]     += p0[d];
                    if (pl >= 1 && pl <= 6) acc[pl - 1][d] += p1[d];
                    if (pl >= 2)            acc[pl - 2][d] += p2[d];
                }
            }
#pragma unroll
            for (int oz = 0; oz < 6; ++oz) {
                uint16_t u0 = f2b(acc[oz][0]), u1 = f2b(acc[oz][1]);
                uint16_t u2 = f2b(acc[oz][2]), u3 = f2b(acc[oz][3]);
                uint2 o;
                o.x = (uint32_t)u0 | ((uint32_t)u1 << 16);
                o.y = (uint32_t)u2 | ((uint32_t)u3 << 16);
                *(uint2*)&dst[(size_t)(z0 + oz) * SD2 + y * SD + c4] = o;
#pragma unroll
                for (int d = 0; d < 4; ++d) ssq += acc[oz][d] * acc[oz][d];
            }
        }
    }

    for (int off = 32; off; off >>= 1) ssq += __shfl_down(ssq, off, 64);
    if ((t & 63) == 0) red[t >> 6] = ssq;
    __syncthreads();
    if (t == 0) atomicAdd(&sums[bc], red[0] + red[1] + red[2] + red[3]);
}

// ---- K3: scores S[b][h][i][j] = sum_n q_i k_j  (MFMA, full n coverage) -------
__global__ __launch_bounds__(256) void k_scores(const bf16* __restrict__ qkv2,
                                                float* __restrict__ scores)
{
    int b = blockIdx.z, h = blockIdx.y;
    const bf16* qb = qkv2 + ((size_t)b * C3 + h * 16) * NSP;
    const bf16* kb = qkv2 + ((size_t)b * C3 + 128 + h * 16) * NSP;
    int t = threadIdx.x, w = t >> 6, lane = t & 63;
    int m = lane & 15, q4 = lane >> 4;
    size_t n0 = (size_t)blockIdx.x * 1024 + (size_t)w * 256 + (size_t)q4 * 8;
    const bf16* qp = qb + (size_t)m * NSP + n0;
    const bf16* kp = kb + (size_t)m * NSP + n0;
    f32x4 acc = (f32x4){0.f, 0.f, 0.f, 0.f};
#pragma unroll
    for (int it = 0; it < 8; ++it) {
        bf16x8 a  = *(const bf16x8*)(qp + it * 32);
        bf16x8 bb = *(const bf16x8*)(kp + it * 32);
        acc = __builtin_amdgcn_mfma_f32_16x16x32_bf16(a, bb, acc, 0, 0, 0);
    }
    float* srow = scores + (size_t)(b * NH + h) * 256;
#pragma unroll
    for (int r = 0; r < 4; ++r)
        atomicAdd(&srow[(q4 * 4 + r) * 16 + m], acc[r]);
}

// ---- K4: normalize + temperature + softmax -----------------------------------
__global__ void k_softmax(const float* __restrict__ scores,
                          const float* __restrict__ sums,
                          const bf16* __restrict__ temp,
                          float* __restrict__ attn)
{
    int t = threadIdx.x;             // t = b*128 + h*16 + i
    int h = (t >> 4) & 7, b = t >> 7;
    float tau = __bfloat162float(temp[h]);
    float invq = 1.f / fmaxf(sqrtf(sums[b * C3 + (t & 127)]), 1e-12f);
    const float* srow = scores + (size_t)t * 16;
    float s[16]; float mx = -3.4e38f;
#pragma unroll
    for (int j = 0; j < 16; ++j) {
        float invk = 1.f / fmaxf(sqrtf(sums[b * C3 + 128 + h * 16 + j]), 1e-12f);
        s[j] = srow[j] * invq * invk * tau;
        mx = fmaxf(mx, s[j]);
    }
    float sum = 0.f;
#pragma unroll
    for (int j = 0; j < 16; ++j) { s[j] = expf(s[j] - mx); sum += s[j]; }
    float inv = 1.f / sum;
    float* arow = attn + (size_t)t * 16;
#pragma unroll
    for (int j = 0; j < 16; ++j) arow[j] = s[j] * inv;
}

// ---- K5: compose W2[b][co][h*16+j] = sum_i proj_w[co][h*16+i]*attn[b][h][i][j]
// (absorbs the attention-apply into the projection: out = W2 @ V, so k_av and
// the outT intermediate are eliminated entirely)
__global__ void k_wproj(const bf16* __restrict__ projw,
                        const float* __restrict__ attn,
                        bf16* __restrict__ w2)
{
    int b = blockIdx.x;
    int t = threadIdx.x;
    int co = t >> 1;                 // 0..127
    int h0 = (t & 1) * 4;            // heads 0..3 or 4..7
    const float* ab = attn + (size_t)b * NH * 256;
    bf16* wr = w2 + (size_t)b * CIN * CIN + (size_t)co * CIN;
#pragma unroll 1
    for (int h = h0; h < h0 + 4; ++h) {
        float pw[16];
#pragma unroll
        for (int i = 0; i < 16; ++i) pw[i] = ldb(&projw[co * CIN + h * 16 + i]);
#pragma unroll 1
        for (int jj = 0; jj < 16; ++jj) {
            float s = 0.f;
#pragma unroll
            for (int i = 0; i < 16; ++i)
                s += pw[i] * ab[h * 256 + i * 16 + jj];
            wr[h * 16 + jj] = __float2bfloat16(s);
        }
    }
}

// ---- K6: out[b][co][n] = sum_j W2[b][co][j] * V[b][j][n] ---------------------
// V = qkv2 channels 256..383, [j][n] row-major; staged transposed into lB[n][j]
// with the same verified 4x4 register-transpose as k_gemm_qkv's bf16 path.
// MFMA loop + C-write identical to the verified k_gemm_bt (Mtotal=CIN, mb=0).
__global__ __launch_bounds__(256) void k_gemm_w2v(const bf16* __restrict__ W2,
                                                  const bf16* __restrict__ qkv2,
                                                  void* __restrict__ Cout,
                                                  const int* __restrict__ flagp)
{
    __shared__ __align__(16) bf16 lA[128 * CIN];
    __shared__ __align__(16) bf16 lB[128 * CIN];
    int b = blockIdx.z;
    size_t nbase = (size_t)blockIdx.x * 128;
    const bf16* gA = W2 + (size_t)b * CIN * CIN;
    const bf16* vb = qkv2 + ((size_t)b * C3 + 256) * NSP + nbase;
    int t = threadIdx.x;

    // stage A (linear): 128x128 bf16 = 2048 uint4 = 8 per thread
#pragma unroll
    for (int i = 0; i < 8; ++i) {
        int off = (i * 256 + t) * 8;
        *(uint4*)&lA[off] = *(const uint4*)&gA[off];
    }

    // stage B transposed from V[j][n] -> lB[n][j]
    int cq = t >> 5, nq = t & 31;
#pragma unroll
    for (int p = 0; p < 4; ++p) {
        int c0 = p * 32 + cq * 4;
        uint2 rv[4];
#pragma unroll
        for (int r = 0; r < 4; ++r)
            rv[r] = *(const uint2*)&vb[(size_t)(c0 + r) * NSP + nq * 4];
#pragma unroll
        for (int e = 0; e < 4; ++e) {
            ushort4 o;
            o.x = (uint16_t)(e < 2 ? (rv[0].x >> (e * 16)) : (rv[0].y >> ((e - 2) * 16)));
            o.y = (uint16_t)(e < 2 ? (rv[1].x >> (e * 16)) : (rv[1].y >> ((e - 2) * 16)));
            o.z = (uint16_t)(e < 2 ? (rv[2].x >> (e * 16)) : (rv[2].y >> ((e - 2) * 16)));
            o.w = (uint16_t)(e < 2 ? (rv[3].x >> (e * 16)) : (rv[3].y >> ((e - 2) * 16)));
            *(ushort4*)&lB[(nq * 4 + e) * CIN + c0] = o;
        }
    }
    __syncthreads();

    int wave = t >> 6, lane = t & 63;
    int wm = (wave & 1) * 64, wn = (wave >> 1) * 64;
    int lr = lane & 15, lq = lane >> 4;
    f32x4 acc[4][4];
#pragma unroll
    for (int mi = 0; mi < 4; ++mi)
#pragma unroll
        for (int ni = 0; ni < 4; ++ni) acc[mi][ni] = (f32x4){0.f, 0.f, 0.f, 0.f};

#pragma unroll
    for (int ks = 0; ks < 4; ++ks) {
        int kof = ks * 32 + lq * 8;
        bf16x8 af[4], bfv[4];
#pragma unroll
        for (int mi = 0; mi < 4; ++mi)
            af[mi] = *(const bf16x8*)&lA[(wm + mi * 16 + lr) * CIN + kof];
#pragma unroll
        for (int ni = 0; ni < 4; ++ni)
            bfv[ni] = *(const bf16x8*)&lB[(wn + ni * 16 + lr) * CIN + kof];
#pragma unroll
        for (int mi = 0; mi < 4; ++mi)
#pragma unroll
            for (int ni = 0; ni < 4; ++ni)
                acc[mi][ni] = __builtin_amdgcn_mfma_f32_16x16x32_bf16(
                    af[mi], bfv[ni], acc[mi][ni], 0, 0, 0);
    }

    int f32o = *flagp;
    size_t cb = ((size_t)b * CIN) * NSP + nbase;
    if (f32o) {
        float* Cb = (float*)Cout + cb;
#pragma unroll
        for (int mi = 0; mi < 4; ++mi)
#pragma unroll
            for (int ni = 0; ni < 4; ++ni)
#pragma unroll
                for (int r = 0; r < 4; ++r)
                    Cb[(size_t)(wm + mi * 16 + lq * 4 + r) * NSP + wn + ni * 16 + lr]
                        = acc[mi][ni][r];
    } else {
        bf16* Cb = (bf16*)Cout + cb;
#pragma unroll
        for (int mi = 0; mi < 4; ++mi)
#pragma unroll
            for (int ni = 0; ni < 4; ++ni)
#pragma unroll
                for (int r = 0; r < 4; ++r)
                    Cb[(size_t)(wm + mi * 16 + lq * 4 + r) * NSP + wn + ni * 16 + lr]
                        = __float2bfloat16(acc[mi][ni][r]);
    }
}

// ---- host --------------------------------------------------------------------
extern "C" void kernel_launch(void* const* d_in, const int* in_sizes, int n_in,
                              void* d_out, int out_size, void* d_ws, size_t ws_size,
                              hipStream_t stream)
{
    const void *px = nullptr, *pq = nullptr, *pd = nullptr, *pp = nullptr, *pt = nullptr;
    for (int i = 0; i < n_in; ++i) {
        switch (in_sizes[i]) {
            case 28311552: px = d_in[i]; break;   // x
            case 49152:    pq = d_in[i]; break;   // qkv_w
            case 10368:    pd = d_in[i]; break;   // dw_w
            case 16384:    pp = d_in[i]; break;   // proj_w
            case 8:        pt = d_in[i]; break;   // temperature
        }
    }
    const size_t required = NQ * 4 + (1u << 20);
    if (!px || !pq || !pd || !pp || !pt || ws_size < required) {
        (void)hipMemsetAsync(d_out, 0, (size_t)out_size * 2, stream);
        return;
    }

    char* ws = (char*)d_ws;
    bf16* qkv1 = (bf16*)ws;                       // NQ bf16
    bf16* qkv2 = (bf16*)(ws + NQ * 2);            // NQ bf16
    char* small = ws + NQ * 4;
    int*   flag   = (int*)small;
    float* sums   = (float*)(small + 256);
    float* scores = (float*)(small + 8192);
    float* attn   = (float*)(small + 24576);
    bf16*  wbuf   = (bf16*)(small + 40960);       // ends at 40960+151824=192784
    bf16*  w2buf  = (bf16*)(small + 196608);      // NB*128*128 bf16 = 64KB

    (void)hipMemsetAsync(small, 0, 40960, stream);  // flag, sums, scores, attn
    k_sniff<<<1, 256, 0, stream>>>((const uint16_t*)px, flag);
    k_cvtw<<<(WTOTAL + 255) / 256, 256, 0, stream>>>(pq, pd, pp, pt, wbuf, flag);
    k_gemm_qkv<<<dim3(864 * 3, 1, NB), 256, 0, stream>>>(
        wbuf + WOFF_QKVW, px, qkv1, flag);
    k_dwconv<<<dim3(NB * C3, 8), 256, 0, stream>>>(qkv1, wbuf + WOFF_DWW, qkv2, sums);
    k_scores<<<dim3(108, NH, NB), 256, 0, stream>>>(qkv2, scores);
    k_softmax<<<1, 256, 0, stream>>>(scores, sums, wbuf + WOFF_TEMP, attn);
    k_wproj<<<NB, 256, 0, stream>>>(wbuf + WOFF_PROJ, attn, w2buf);
    k_gemm_w2v<<<dim3(864, 1, NB), 256, 0, stream>>>(w2buf, qkv2, d_out, flag);
}